// Round 19
// baseline (285.392 us; speedup 1.0000x reference)
//
#include <hip/hip_runtime.h>

#define D_CODES 2048
#define C_DIM   256
#define MOM     0.99f
#define ONE_M   0.01f
#define EPSI    1e-5f
#define TAU     0.16f
#define RCAP    16384
#define SBCAP   2304

// output offsets (floats)
#define Q_OFF    0
#define LOSS_OFF 16777216
#define IDS_OFF  16777217
#define NE_OFF   16842753
#define NCS_OFF  17367041
#define NEA_OFF  17369089

// workspace offsets (floats)
#define WS_ICNT    0
#define WS_CNTF    2048
#define WS_OFFS    4096
#define WS_CURS    6144
#define WS_SUMX2   10240
#define WS_NTOT    11264
#define WS_RCNT    11268
#define WS_NSB     11269
#define WS_NORMS   11272
#define WS_RLIST   13320
#define WS_ESUM    29704
#define WS_E2      553992
#define WS_KEYH    816136
#define WS_M2H     1340424
#define WS_PLIST   1602568
#define WS_SBCODE  1668104
#define WS_SBSTART 1670408
#define WS_SBINFO  1672712
#define WS_LOSSP   1675016

typedef _Float16 half8 __attribute__((ext_vector_type(8)));
typedef __attribute__((ext_vector_type(4))) float f32x4;
typedef unsigned long long u64;

__device__ __forceinline__ f32x4 MFH(half8 a, half8 b, f32x4 c) {
    return __builtin_amdgcn_mfma_f32_16x16x32_f16(a, b, c, 0, 0, 0);
}
__device__ __forceinline__ unsigned enc_f(float v) {
    unsigned u = __float_as_uint(v);
    return (u & 0x80000000u) ? ~u : (u | 0x80000000u);
}
__device__ __forceinline__ float dec_f(unsigned u) {
    return (u & 0x80000000u) ? __uint_as_float(u & 0x7FFFFFFFu)
                             : __uint_as_float(~u);
}
__device__ __forceinline__ unsigned short h_bits(_Float16 h) {
    union { _Float16 f; unsigned short u; } c; c.f = h; return c.u;
}

// grid 2048: esum zero everywhere; 0-63 eprep+norms; 64-71 icnt; 72-80 lossp; 81 rcnt;
// 128-383 embed transpose -> etg; 384-1407 x transpose -> xt2 (FP16, 32MB) + sumx2
__global__ __launch_bounds__(256) void k_init(
    const float* __restrict__ embed, const float* __restrict__ x,
    float* __restrict__ e2f, float* __restrict__ norms,
    float* __restrict__ esum, int* __restrict__ icnt,
    float* __restrict__ lossp, unsigned* __restrict__ rcnt,
    float* __restrict__ etg, unsigned short* __restrict__ xt2,
    float* __restrict__ sumx2p)
{
    __shared__ float sh[8228];        // nrm[32] | xs2[32][257] + wred[4]
    const int b = blockIdx.x, t = threadIdx.x;
    esum[(size_t)b * 256 + t] = 0.f;
    if (b < 64) {
        if (t < 32) sh[t] = 0.f;
        __syncthreads();
        char* e2 = (char*)e2f;
        const int s = b;
        #pragma unroll
        for (int it = 0; it < 4; ++it) {
            int u = it * 256 + t;
            int r = u >> 9, kc = (u >> 6) & 7, l = u & 63;
            int code = s * 32 + r * 16 + (l & 15);
            int ch0  = kc * 32 + ((l >> 4) << 3);
            const float* src = embed + (size_t)code * C_DIM + ch0;
            float4 v0 = *(const float4*)src;
            float4 v1 = *(const float4*)(src + 4);
            float vv[8] = {v0.x, v0.y, v0.z, v0.w, v1.x, v1.y, v1.z, v1.w};
            half8 hh;
            float p = 0.f;
            #pragma unroll
            for (int j = 0; j < 8; ++j) { hh[j] = (_Float16)vv[j]; p += vv[j] * vv[j]; }
            atomicAdd(&sh[r * 16 + (l & 15)], p);
            char* dst = e2 + (size_t)s * 16384 + (size_t)((r * 8 + kc) * 64 + l) * 16;
            *(half8*)dst = hh;
        }
        __syncthreads();
        if (t < 32) norms[s * 32 + t] = sh[t];
    } else if (b < 72) {
        icnt[(b - 64) * 256 + t] = 0;
    } else if (b < 81) {
        int j = (b - 72) * 256 + t;
        if (j < SBCAP) lossp[j] = 0.f;
    } else if (b == 81) {
        if (t == 0) *rcnt = 0u;
    } else if (b >= 128 && b < 384) {
        int code0 = (b - 128) * 8;
        #pragma unroll
        for (int j = 0; j < 8; ++j) {
            float v = embed[(size_t)(code0 + j) * C_DIM + t];
            etg[(size_t)t * D_CODES + code0 + j] = v;
        }
    } else if (b >= 384 && b < 1408) {
        float (*xs2)[257] = (float(*)[257])sh;
        float* wred = sh + 8224;
        const int xb = b - 384;
        const int bi = xb >> 6;
        const int hi = xb & 63;
        const int wl = t & 31;
        const int chh = t >> 5;
        float sx2 = 0.f;
        #pragma unroll
        for (int pass = 0; pass < 2; ++pass) {
            __syncthreads();
            #pragma unroll 8
            for (int k = 0; k < 32; ++k) {
                int ch = k * 8 + chh;
                float v = x[((size_t)(bi * C_DIM + ch)) * 4096 + hi * 64 + pass * 32 + wl];
                sx2 += v * v;
                xs2[wl][ch] = v;
            }
            __syncthreads();
            // pack fp16 pairs: 2 pixels per iteration, 128 threads per pixel
            const int pxl = t >> 7;          // 0..1
            const int ch2 = (t & 127) * 2;
            #pragma unroll 4
            for (int j2 = 0; j2 < 16; ++j2) {
                int pl = j2 * 2 + pxl;       // 0..31
                float v0 = xs2[pl][ch2];
                float v1 = xs2[pl][ch2 + 1];
                unsigned pack = ((unsigned)h_bits((_Float16)v1) << 16)
                              | h_bits((_Float16)v0);
                size_t n = (size_t)bi * 4096 + (size_t)(pass * 32 + pl) * 64 + hi;
                *(unsigned*)(xt2 + n * C_DIM + ch2) = pack;
            }
        }
        #pragma unroll
        for (int o = 32; o; o >>= 1) sx2 += __shfl_down(sx2, o);
        __syncthreads();
        if ((t & 63) == 0) wred[t >> 6] = sx2;
        __syncthreads();
        if (t == 0) sumx2p[xb] = wred[0] + wred[1] + wred[2] + wred[3];
    }
}

// grid 512: blk = (bi*8 + q)*4 + p. Block = 512 pixels (hi in [8q,8q+8), all wi);
// wave w owns 2 hi rows (8q+2w, 8q+2w+1) x 64 wi = 128 px as nt=0..7 sub-tiles:
// wi = (nt&3)*16 + (l&15), hi = 8q + 2w + (nt>>3... (nt>>2)). Quarter p scans codes
// [p*512,+512). r19 RATIONALE: k_main was L2-BW bound on redundant per-wave e2
// re-reads (4096 waves x 256KB = 1GB ~ 29-58us wall). nt=8 HALVES wave count ->
// 512MB e2 traffic, MFMA:load ratio doubles. Registers ~360 VGPR + 32 AGPR ->
// 1 wave/SIMD: deliberate ILP-over-TLP (dbuf + 8 indep MFMA chains hide latency).
// Spill signature to watch: WRITE_SIZE >> 4MB.
__global__ __launch_bounds__(256, 1) void k_main(
    const unsigned short* __restrict__ xt2, const float* __restrict__ e2f,
    const float* __restrict__ norms, u64* __restrict__ keyh,
    float* __restrict__ m2h)
{
    __shared__ float nlds[512];
    const int t  = threadIdx.x;
    const int l  = t & 63;
    const int w  = __builtin_amdgcn_readfirstlane(t >> 6);
    const int blk = blockIdx.x;
    const int p  = blk & 3;
    const int q  = (blk >> 2) & 7;
    const int bi = blk >> 5;
    const char* e2 = (const char*)e2f + (size_t)p * 262144 + (size_t)l * 16;

    // stage this quarter's norms into LDS (2KB)
    if (t < 128) *(float4*)&nlds[t * 4] = *(const float4*)(norms + p * 512 + t * 4);

    // B-frags direct from xt2: nt sub-tile -> pixel (bi, hi=8q+2w+(nt>>2),
    // wi=(nt&3)*16+(l&15)), channels (l>>4)*8 + c*32
    half8 bx[8][8];
    {
        const _Float16* xth = (const _Float16*)xt2;
        #pragma unroll
        for (int nt = 0; nt < 8; ++nt) {
            int wi = (nt & 3) * 16 + (l & 15);
            int hi = 8 * q + 2 * w + (nt >> 2);
            size_t n = (size_t)bi * 4096 + (size_t)wi * 64 + hi;
            const _Float16* base = xth + n * C_DIM + ((l >> 4) << 3);
            #pragma unroll
            for (int c = 0; c < 8; ++c)
                bx[nt][c] = *(const half8*)(base + c * 32);
        }
    }
    __syncthreads();

    float m1[8], m2[8];
    int   i1[8];
    #pragma unroll
    for (int nt = 0; nt < 8; ++nt) { m1[nt] = -3.4e38f; m2[nt] = -3.4e38f; i1[nt] = 0; }

    half8 ahA[8], ahB[8];
    auto loadbuf = [&](half8* buf, int ri) {
        const char* pp = e2 + (size_t)ri * 8192;
        #pragma unroll
        for (int kc = 0; kc < 8; ++kc)
            buf[kc] = *(const half8*)(pp + kc * 1024);
    };
    auto compute = [&](const half8* ah, int ri) {
        float4 nrm = *(const float4*)&nlds[ri * 16 + ((l >> 4) << 2)];
        f32x4 z = {0.f, 0.f, 0.f, 0.f};
        f32x4 aA[8] = {z, z, z, z, z, z, z, z};
        #pragma unroll
        for (int kc = 0; kc < 8; ++kc) {
            #pragma unroll
            for (int nt = 0; nt < 8; ++nt)
                aA[nt] = MFH(ah[kc], bx[nt][kc], aA[nt]);
        }
        int c0 = p * 512 + ri * 16 + ((l >> 4) << 2);
        float nr[4] = {nrm.x, nrm.y, nrm.z, nrm.w};
        #pragma unroll
        for (int nt = 0; nt < 8; ++nt) {
            #pragma unroll
            for (int reg = 0; reg < 4; ++reg) {
                float sc = 2.f * aA[nt][reg] - nr[reg];
                int code = c0 + reg;
                if (sc > m1[nt]) { m2[nt] = m1[nt]; m1[nt] = sc; i1[nt] = code; }
                else             { m2[nt] = fmaxf(m2[nt], sc); }
            }
        }
    };

    loadbuf(ahA, 0);
    for (int ri = 0; ri < 32; ri += 2) {
        loadbuf(ahB, ri + 1);
        compute(ahA, ri);
        if (ri + 2 < 32) loadbuf(ahA, ri + 2);
        compute(ahB, ri + 1);
    }

    #pragma unroll
    for (int nt = 0; nt < 8; ++nt) {
        float a1 = m1[nt], a2 = m2[nt];
        int   ai = i1[nt];
        #pragma unroll
        for (int off = 16; off <= 32; off <<= 1) {
            float o1 = __shfl_xor(a1, off);
            int   oi = __shfl_xor(ai, off);
            float o2 = __shfl_xor(a2, off);
            if (o1 > a1)       { a2 = fmaxf(a1, o2); a1 = o1; ai = oi; }
            else if (o1 == a1) { if (oi < ai) ai = oi; a2 = a1; }
            else               { a2 = fmaxf(a2, o1); }
        }
        if (l < 16) {
            int wi = (nt & 3) * 16 + l;
            int hi = 8 * q + 2 * w + (nt >> 2);
            int n = (bi << 12) + (wi << 6) + hi;
            keyh[((size_t)p << 16) + n] = ((u64)enc_f(a1) << 32) | (unsigned)(~ai);
            m2h[(p << 16) + n] = a2;
        }
    }
}

// grid 256: exact 4-way union top-2 merge -> ids + LDS-aggregated histogram +
// near-tie flags. LDS hist caps hot-code global atomics at <=256 (was ~2600
// same-address serialized adds).
__global__ __launch_bounds__(256) void k_merge(
    const u64* __restrict__ keyh, const float* __restrict__ m2h,
    float* __restrict__ out, int* __restrict__ icnt,
    unsigned* __restrict__ rcnt, int* __restrict__ rlist)
{
    __shared__ int hist[D_CODES];
    const int t = threadIdx.x;
    #pragma unroll
    for (int j = 0; j < 8; ++j) hist[j * 256 + t] = 0;
    __syncthreads();
    int n = blockIdx.x * 256 + t;
    u64 k0 = keyh[n],          k1 = keyh[65536 + n];
    u64 k2 = keyh[131072 + n], k3 = keyh[196608 + n];
    float q0 = m2h[n],          q1 = m2h[65536 + n];
    float q2 = m2h[131072 + n], q3 = m2h[196608 + n];
    bool a01 = k0 >= k1;
    u64  kp01 = a01 ? k0 : k1;
    float sec01 = fmaxf(a01 ? q0 : q1, dec_f((unsigned)((a01 ? k1 : k0) >> 32)));
    bool a23 = k2 >= k3;
    u64  kp23 = a23 ? k2 : k3;
    float sec23 = fmaxf(a23 ? q2 : q3, dec_f((unsigned)((a23 ? k3 : k2) >> 32)));
    bool aW = kp01 >= kp23;
    u64  kW = aW ? kp01 : kp23;
    float second = fmaxf(aW ? sec01 : sec23,
                         dec_f((unsigned)((aW ? kp23 : kp01) >> 32)));
    float sW = dec_f((unsigned)(kW >> 32));
    int code = (int)(~(unsigned)kW);
    out[IDS_OFF + n] = (float)code;
    atomicAdd(&hist[code], 1);
    if (sW - second < TAU) {
        unsigned j = atomicAdd(rcnt, 1u);
        if (j < RCAP) rlist[j] = n;
    }
    __syncthreads();
    #pragma unroll
    for (int j = 0; j < 8; ++j) {
        int c = hist[j * 256 + t];
        if (c) atomicAdd(&icnt[j * 256 + t], c);
    }
}

// grid 512: exact fp32 rescore of flagged pixels (x gathered directly; etg coalesced)
__global__ __launch_bounds__(256) void k_rescue(
    const float* __restrict__ x, const float* __restrict__ etg,
    const float* __restrict__ norms, const unsigned* __restrict__ rcnt,
    const int* __restrict__ rlist, float* __restrict__ out,
    int* __restrict__ icnt)
{
    __shared__ float xs[8][257];
    __shared__ int nn[8];
    __shared__ u64 rk[4][8];
    const int t = threadIdx.x;
    const int l = t & 63;
    const int w = t >> 6;
    int nf = (int)min(*rcnt, (unsigned)RCAP);
    int nch = (nf + 7) >> 3;
    for (int chunk = blockIdx.x; chunk < nch; chunk += gridDim.x) {
        __syncthreads();
        if (t < 8) {
            int idx = chunk * 8 + t;
            nn[t] = rlist[idx < nf ? idx : (nf - 1)];
        }
        __syncthreads();
        #pragma unroll
        for (int p = 0; p < 8; ++p) {
            int n = nn[p];
            int bi = n >> 12, wi = (n >> 6) & 63, hi = n & 63;
            xs[p][t] = x[((size_t)(bi * C_DIM + t)) * 4096 + hi * 64 + wi];
        }
        __syncthreads();
        u64 bk[8];
        #pragma unroll
        for (int p = 0; p < 8; ++p) bk[p] = 0ull;
        #pragma unroll
        for (int rep = 0; rep < 2; ++rep) {
            const int d0 = rep * 1024 + t * 4;
            f32x4 acc[8];
            #pragma unroll
            for (int p = 0; p < 8; ++p) acc[p] = (f32x4){0.f, 0.f, 0.f, 0.f};
            for (int c = 0; c < C_DIM; ++c) {
                float4 e4 = *(const float4*)(etg + (size_t)c * D_CODES + d0);
                f32x4 ev = {e4.x, e4.y, e4.z, e4.w};
                #pragma unroll
                for (int p = 0; p < 8; ++p)
                    acc[p] += xs[p][c] * ev;
            }
            float4 nr = *(const float4*)(norms + d0);
            float nrr[4] = {nr.x, nr.y, nr.z, nr.w};
            #pragma unroll
            for (int p = 0; p < 8; ++p) {
                #pragma unroll
                for (int j = 0; j < 4; ++j) {
                    float sc = 2.f * acc[p][j] - nrr[j];
                    u64 key = ((u64)enc_f(sc) << 32) | (unsigned)(~(d0 + j));
                    if (key > bk[p]) bk[p] = key;
                }
            }
        }
        #pragma unroll
        for (int p = 0; p < 8; ++p) {
            u64 k0 = bk[p];
            #pragma unroll
            for (int o = 32; o; o >>= 1) {
                u64 ok = __shfl_down(k0, o);
                if (ok > k0) k0 = ok;
            }
            if (l == 0) rk[w][p] = k0;
        }
        __syncthreads();
        if (t < 8 && chunk * 8 + t < nf) {
            u64 k0 = rk[0][t];
            if (rk[1][t] > k0) k0 = rk[1][t];
            if (rk[2][t] > k0) k0 = rk[2][t];
            if (rk[3][t] > k0) k0 = rk[3][t];
            int n = nn[t];
            int newid = (int)(~(unsigned)k0);
            int old = (int)out[IDS_OFF + n];
            if (newid != old) {
                out[IDS_OFF + n] = (float)newid;
                atomicAdd(&icnt[old], -1);
                atomicAdd(&icnt[newid], 1);
            }
        }
    }
}

// single block: offsets + sub-block table + cntf + ntot
__global__ __launch_bounds__(256) void k_prefix(const int* __restrict__ icnt,
                                                const float* __restrict__ cs_in,
                                                int* __restrict__ offs,
                                                int* __restrict__ curs,
                                                float* __restrict__ cntf,
                                                int* __restrict__ sbcode,
                                                int* __restrict__ sbstart,
                                                int* __restrict__ sbinfo,
                                                int* __restrict__ nsbtot,
                                                float* __restrict__ ntot) {
    __shared__ int ps[256];
    __shared__ float fs[256];
    const int t = threadIdx.x;
    int c[8], o8[8];
    int s = 0;
    #pragma unroll
    for (int j = 0; j < 8; ++j) c[j] = icnt[t * 8 + j];
    #pragma unroll
    for (int j = 0; j < 8; ++j) { int tmp = c[j]; c[j] = s; s += tmp; }
    ps[t] = s;
    __syncthreads();
    for (int off = 1; off < 256; off <<= 1) {
        int v = (t >= off) ? ps[t - off] : 0;
        __syncthreads();
        ps[t] += v;
        __syncthreads();
    }
    int base = ps[t] - s;
    #pragma unroll
    for (int j = 0; j < 8; ++j) {
        int o = base + c[j];
        o8[j] = o;
        offs[t * 8 + j] = o;
        curs[t * 8 + j] = o;
        cntf[t * 8 + j] = (float)(icnt[t * 8 + j]);
    }
    int s2 = 0;
    int nb[8];
    #pragma unroll
    for (int j = 0; j < 8; ++j) {
        int cnt = icnt[t * 8 + j];
        nb[j] = (cnt + 255) >> 8;
        s2 += nb[j];
    }
    __syncthreads();
    ps[t] = s2;
    __syncthreads();
    for (int off = 1; off < 256; off <<= 1) {
        int v = (t >= off) ? ps[t - off] : 0;
        __syncthreads();
        ps[t] += v;
        __syncthreads();
    }
    int pos = ps[t] - s2;
    #pragma unroll
    for (int j = 0; j < 8; ++j) {
        int code = t * 8 + j;
        int cnt = icnt[code];
        int n = nb[j];
        for (int k = 0; k < n; ++k) {
            sbcode[pos]  = code;
            sbstart[pos] = o8[j] + k * 256;
            int len = cnt - k * 256; if (len > 256) len = 256;
            sbinfo[pos]  = len | ((n > 1) ? (1 << 16) : 0);
            ++pos;
        }
    }
    if (t == 255) *nsbtot = ps[255];
    // ntot = 0.99 * sum(cs_in) + 0.01 * 65536 (assignment-independent)
    float s3 = 0.f;
    #pragma unroll
    for (int j = 0; j < 8; ++j) s3 += cs_in[t * 8 + j];
    fs[t] = s3;
    __syncthreads();
    for (int o = 128; o; o >>= 1) { if (t < o) fs[t] += fs[t + o]; __syncthreads(); }
    if (t == 0) *ntot = MOM * fs[0] + ONE_M * 65536.0f;
}

__global__ __launch_bounds__(256) void k_scatter(const float* __restrict__ out,
                                                 int* __restrict__ curs,
                                                 int* __restrict__ plist) {
    int n = blockIdx.x * 256 + threadIdx.x;
    int id = (int)out[IDS_OFF + n];
    int pos = atomicAdd(&curs[id], 1);
    plist[pos] = n;
}

// grid-stride over sub-blocks: dense esum partials (fp16 xt2 reads, fp32 accum)
__global__ __launch_bounds__(256) void k_esum(
    const unsigned short* __restrict__ xt2, const float* __restrict__ embed,
    const float* __restrict__ norms, const int* __restrict__ sbcode,
    const int* __restrict__ sbstart, const int* __restrict__ sbinfo,
    const int* __restrict__ plist, const int* __restrict__ nsbtot,
    float* __restrict__ esum, float* __restrict__ lossp)
{
    __shared__ int   ns[256];
    __shared__ float red[256];
    const _Float16* xth = (const _Float16*)xt2;
    const int t = threadIdx.x;
    const int total = *nsbtot;
    for (int sb = blockIdx.x; sb < total; sb += gridDim.x) {
        const int d     = sbcode[sb];
        const int start = sbstart[sb];
        const int info  = sbinfo[sb];
        const int len   = info & 0xFFFF;
        const bool multi = (info >> 16) != 0;
        __syncthreads();
        if (t < len) ns[t] = plist[start + t];
        __syncthreads();
        float acc = 0.f;
        #pragma unroll 8
        for (int i = 0; i < len; ++i)
            acc += (float)xth[(size_t)ns[i] * C_DIM + t];
        if (multi) atomicAdd(&esum[(size_t)t * D_CODES + d], acc);
        else       esum[(size_t)t * D_CODES + d] = acc;
        red[t] = acc * embed[(size_t)d * C_DIM + t];
        __syncthreads();
        for (int o = 128; o; o >>= 1) {
            if (t < o) red[t] += red[t + o];
            __syncthreads();
        }
        if (t == 0) lossp[sb] = 2.f * red[0] - (float)len * norms[d];
    }
}

// grid 3073: blocks 0-1023 quantized write; 1024-3071 embed-EMA+new_embed (+NCS);
// block 3072 loss
__global__ __launch_bounds__(256) void k_post(
    const float* __restrict__ embed, const float* __restrict__ cs_in,
    const float* __restrict__ cntf, const float* __restrict__ embed_avg,
    const float* __restrict__ esum, const float* __restrict__ ntotp,
    const float* __restrict__ lossp, const float* __restrict__ sumx2p,
    float* __restrict__ out)
{
    __shared__ float shm[8456];       // quant: ids_s[64]+es[32][257]; final: sm[256]
    const int b = blockIdx.x;
    const int t = threadIdx.x;
    if (b < 1024) {
        int* ids_s = (int*)shm;
        float (*es)[257] = (float(*)[257])(shm + 64);
        const int bi = b >> 6;
        const int hi = b & 63;
        const int wl = t & 31;
        const int cg = t >> 5;
        if (t < 64) ids_s[t] = (int)out[IDS_OFF + ((size_t)bi << 12) + (t << 6) + hi];
        __syncthreads();
        #pragma unroll
        for (int pass = 0; pass < 2; ++pass) {
            #pragma unroll 8
            for (int p = 0; p < 32; ++p) {
                es[p][t] = embed[(size_t)ids_s[pass * 32 + p] * C_DIM + t];
            }
            __syncthreads();
            #pragma unroll 8
            for (int k = 0; k < 32; ++k) {
                int ch = k * 8 + cg;
                out[Q_OFF + ((size_t)(bi * C_DIM + ch)) * 4096 + hi * 64 + pass * 32 + wl]
                    = es[wl][ch];
            }
            __syncthreads();
        }
    } else if (b < 3072) {
        int bb = b - 1024;
        int ch = bb >> 3;
        int d  = ((bb & 7) << 8) + t;
        float ntot = *ntotp;
        float ncs  = MOM * cs_in[d] + ONE_M * cntf[d];
        if (bb < 8) out[NCS_OFF + d] = ncs;
        float csm  = ntot * (ncs + EPSI) / (ntot + (float)D_CODES * EPSI);
        size_t i = (size_t)ch * D_CODES + d;
        float nea = MOM * embed_avg[i] + ONE_M * esum[i];
        out[NEA_OFF + i] = nea;
        out[NE_OFF + (size_t)d * C_DIM + ch] = nea / csm;
    } else {
        float* sm = shm;
        float s1 = 0.f;
        for (int i = t; i < 1024; i += 256) s1 += sumx2p[i];
        float s2 = 0.f;
        for (int i = t; i < SBCAP; i += 256) s2 += lossp[i];
        sm[t] = s1 - s2;
        __syncthreads();
        for (int o = 128; o; o >>= 1) { if (t < o) sm[t] += sm[t + o]; __syncthreads(); }
        if (t == 0) out[LOSS_OFF] = sm[0] / 16777216.f;
    }
}

extern "C" void kernel_launch(void* const* d_in, const int* in_sizes, int n_in,
                              void* d_out, int out_size, void* d_ws, size_t ws_size,
                              hipStream_t stream) {
    const float* x     = (const float*)d_in[0];
    const float* embed = (const float*)d_in[1];
    const float* cs    = (const float*)d_in[2];
    const float* ea    = (const float*)d_in[3];
    float* out = (float*)d_out;
    float* ws  = (float*)d_ws;
    int*      icnt    = (int*)(ws + WS_ICNT);
    float*    cntf    = ws + WS_CNTF;
    int*      offs    = (int*)(ws + WS_OFFS);
    int*      curs    = (int*)(ws + WS_CURS);
    float*    sumx2p  = ws + WS_SUMX2;
    float*    ntot    = ws + WS_NTOT;
    unsigned* rcnt    = (unsigned*)(ws + WS_RCNT);
    int*      nsbtot  = (int*)(ws + WS_NSB);
    float*    norms   = ws + WS_NORMS;
    int*      rlist   = (int*)(ws + WS_RLIST);
    float*    esum    = ws + WS_ESUM;
    float*    e2      = ws + WS_E2;
    u64*      keyh    = (u64*)(ws + WS_KEYH);
    float*    m2h     = ws + WS_M2H;
    int*      plist   = (int*)(ws + WS_PLIST);
    int*      sbcode  = (int*)(ws + WS_SBCODE);
    int*      sbstart = (int*)(ws + WS_SBSTART);
    int*      sbinfo  = (int*)(ws + WS_SBINFO);
    float*    lossp   = ws + WS_LOSSP;
    unsigned short* xt2 = (unsigned short*)(out + Q_OFF); // fp16 xT, overwritten by k_post
    float*    etg     = out + NEA_OFF;  // embed^T scratch, overwritten by k_post

    k_init<<<2048, 256, 0, stream>>>(embed, x, e2, norms, esum, icnt, lossp, rcnt,
                                     etg, xt2, sumx2p);
    k_main<<<512, 256, 0, stream>>>(xt2, e2, norms, keyh, m2h);
    k_merge<<<256, 256, 0, stream>>>(keyh, m2h, out, icnt, rcnt, rlist);
    k_rescue<<<512, 256, 0, stream>>>(x, etg, norms, rcnt, rlist, out, icnt);
    k_prefix<<<1, 256, 0, stream>>>(icnt, cs, offs, curs, cntf, sbcode, sbstart,
                                    sbinfo, nsbtot, ntot);
    k_scatter<<<256, 256, 0, stream>>>(out, curs, plist);
    k_esum<<<SBCAP, 256, 0, stream>>>(xt2, embed, norms, sbcode, sbstart, sbinfo,
                                      plist, nsbtot, esum, lossp);
    k_post<<<3073, 256, 0, stream>>>(embed, cs, cntf, ea, esum, ntot, lossp,
                                     sumx2p, out);
}

// Round 20
// 255.426 us; speedup vs baseline: 1.1173x; 1.1173x over previous
//
#include <hip/hip_runtime.h>

#define D_CODES 2048
#define C_DIM   256
#define MOM     0.99f
#define ONE_M   0.01f
#define EPSI    1e-5f
#define TAU     0.16f
#define RCAP    16384
#define SBCAP   2304

// output offsets (floats)
#define Q_OFF    0
#define LOSS_OFF 16777216
#define IDS_OFF  16777217
#define NE_OFF   16842753
#define NCS_OFF  17367041
#define NEA_OFF  17369089

// workspace offsets (floats)
#define WS_ICNT    0
#define WS_CNTF    2048
#define WS_OFFS    4096
#define WS_CURS    6144
#define WS_SUMX2   10240
#define WS_NTOT    11264
#define WS_RCNT    11268
#define WS_NSB     11269
#define WS_NORMS   11272
#define WS_RLIST   13320
#define WS_ESUM    29704
#define WS_E2      553992
#define WS_KEYH    816136
#define WS_M2H     1340424
#define WS_PLIST   1602568
#define WS_SBCODE  1668104
#define WS_SBSTART 1670408
#define WS_SBINFO  1672712
#define WS_LOSSP   1675016

typedef _Float16 half8 __attribute__((ext_vector_type(8)));
typedef __attribute__((ext_vector_type(4))) float f32x4;
typedef unsigned long long u64;

__device__ __forceinline__ f32x4 MFH(half8 a, half8 b, f32x4 c) {
    return __builtin_amdgcn_mfma_f32_16x16x32_f16(a, b, c, 0, 0, 0);
}
__device__ __forceinline__ unsigned enc_f(float v) {
    unsigned u = __float_as_uint(v);
    return (u & 0x80000000u) ? ~u : (u | 0x80000000u);
}
__device__ __forceinline__ float dec_f(unsigned u) {
    return (u & 0x80000000u) ? __uint_as_float(u & 0x7FFFFFFFu)
                             : __uint_as_float(~u);
}
__device__ __forceinline__ unsigned short h_bits(_Float16 h) {
    union { _Float16 f; unsigned short u; } c; c.f = h; return c.u;
}

// grid 2048: esum zero everywhere; 0-63 eprep+norms; 64-71 icnt; 72-80 lossp; 81 rcnt;
// 128-383 embed transpose -> etg; 384-1407 x transpose -> xt2 (FP16, 32MB) + sumx2
__global__ __launch_bounds__(256) void k_init(
    const float* __restrict__ embed, const float* __restrict__ x,
    float* __restrict__ e2f, float* __restrict__ norms,
    float* __restrict__ esum, int* __restrict__ icnt,
    float* __restrict__ lossp, unsigned* __restrict__ rcnt,
    float* __restrict__ etg, unsigned short* __restrict__ xt2,
    float* __restrict__ sumx2p)
{
    __shared__ float sh[8228];        // nrm[32] | xs2[32][257] + wred[4]
    const int b = blockIdx.x, t = threadIdx.x;
    esum[(size_t)b * 256 + t] = 0.f;
    if (b < 64) {
        if (t < 32) sh[t] = 0.f;
        __syncthreads();
        char* e2 = (char*)e2f;
        const int s = b;
        #pragma unroll
        for (int it = 0; it < 4; ++it) {
            int u = it * 256 + t;
            int r = u >> 9, kc = (u >> 6) & 7, l = u & 63;
            int code = s * 32 + r * 16 + (l & 15);
            int ch0  = kc * 32 + ((l >> 4) << 3);
            const float* src = embed + (size_t)code * C_DIM + ch0;
            float4 v0 = *(const float4*)src;
            float4 v1 = *(const float4*)(src + 4);
            float vv[8] = {v0.x, v0.y, v0.z, v0.w, v1.x, v1.y, v1.z, v1.w};
            half8 hh;
            float p = 0.f;
            #pragma unroll
            for (int j = 0; j < 8; ++j) { hh[j] = (_Float16)vv[j]; p += vv[j] * vv[j]; }
            atomicAdd(&sh[r * 16 + (l & 15)], p);
            char* dst = e2 + (size_t)s * 16384 + (size_t)((r * 8 + kc) * 64 + l) * 16;
            *(half8*)dst = hh;
        }
        __syncthreads();
        if (t < 32) norms[s * 32 + t] = sh[t];
    } else if (b < 72) {
        icnt[(b - 64) * 256 + t] = 0;
    } else if (b < 81) {
        int j = (b - 72) * 256 + t;
        if (j < SBCAP) lossp[j] = 0.f;
    } else if (b == 81) {
        if (t == 0) *rcnt = 0u;
    } else if (b >= 128 && b < 384) {
        int code0 = (b - 128) * 8;
        #pragma unroll
        for (int j = 0; j < 8; ++j) {
            float v = embed[(size_t)(code0 + j) * C_DIM + t];
            etg[(size_t)t * D_CODES + code0 + j] = v;
        }
    } else if (b >= 384 && b < 1408) {
        float (*xs2)[257] = (float(*)[257])sh;
        float* wred = sh + 8224;
        const int xb = b - 384;
        const int bi = xb >> 6;
        const int hi = xb & 63;
        const int wl = t & 31;
        const int chh = t >> 5;
        float sx2 = 0.f;
        #pragma unroll
        for (int pass = 0; pass < 2; ++pass) {
            __syncthreads();
            #pragma unroll 8
            for (int k = 0; k < 32; ++k) {
                int ch = k * 8 + chh;
                float v = x[((size_t)(bi * C_DIM + ch)) * 4096 + hi * 64 + pass * 32 + wl];
                sx2 += v * v;
                xs2[wl][ch] = v;
            }
            __syncthreads();
            // pack fp16 pairs: 2 pixels per iteration, 128 threads per pixel
            const int pxl = t >> 7;          // 0..1
            const int ch2 = (t & 127) * 2;
            #pragma unroll 4
            for (int j2 = 0; j2 < 16; ++j2) {
                int pl = j2 * 2 + pxl;       // 0..31
                float v0 = xs2[pl][ch2];
                float v1 = xs2[pl][ch2 + 1];
                unsigned pack = ((unsigned)h_bits((_Float16)v1) << 16)
                              | h_bits((_Float16)v0);
                size_t n = (size_t)bi * 4096 + (size_t)(pass * 32 + pl) * 64 + hi;
                *(unsigned*)(xt2 + n * C_DIM + ch2) = pack;
            }
        }
        #pragma unroll
        for (int o = 32; o; o >>= 1) sx2 += __shfl_down(sx2, o);
        __syncthreads();
        if ((t & 63) == 0) wred[t >> 6] = sx2;
        __syncthreads();
        if (t == 0) sumx2p[xb] = wred[0] + wred[1] + wred[2] + wred[3];
    }
}

// grid 512: blk = (bi*16 + q)*2 + h. Block = 256 pixels (hi in [4q,4q+4), all wi);
// wave w owns hi=4q+w (64 px = nt 0..3 x 16 lanes); half h scans codes [h*1024,+1024).
// REVERTED to the r17 shape (83.7us measured): nt=4, 2 waves/SIMD. r18 (quarters,
// 4 blocks/CU) was neutral; r19 (nt=8, 1 wave/SIMD) regressed to 117us -- k_main is
// latency-bound at the wave-schedule level and 2 waves/SIMD is the sweet spot.
// B-frags direct from xt2; direct-L2 e2 loads + register double-buffer + LDS norms.
__global__ __launch_bounds__(256, 1) void k_main(
    const unsigned short* __restrict__ xt2, const float* __restrict__ e2f,
    const float* __restrict__ norms, u64* __restrict__ keyh,
    float* __restrict__ m2h)
{
    __shared__ float nlds[1024];
    const int t  = threadIdx.x;
    const int l  = t & 63;
    const int w  = __builtin_amdgcn_readfirstlane(t >> 6);
    const int blk = blockIdx.x;
    const int h  = blk & 1;
    const int q  = (blk >> 1) & 15;
    const int bi = blk >> 5;
    const char* e2 = (const char*)e2f + (size_t)h * 32 * 16384 + (size_t)l * 16;

    // stage this half's norms into LDS (4KB)
    *(float4*)&nlds[t * 4] = *(const float4*)(norms + h * 1024 + t * 4);

    // B-frags direct from xt2: pixel (bi, hi=4q+w, wi=nt*16+(l&15)), chs (l>>4)*8 + c*32
    half8 bx[4][8];
    {
        const _Float16* xth = (const _Float16*)xt2;
        #pragma unroll
        for (int nt = 0; nt < 4; ++nt) {
            int wi = nt * 16 + (l & 15);
            size_t n = (size_t)bi * 4096 + (size_t)wi * 64 + 4 * q + w;
            const _Float16* base = xth + n * C_DIM + ((l >> 4) << 3);
            #pragma unroll
            for (int c = 0; c < 8; ++c)
                bx[nt][c] = *(const half8*)(base + c * 32);
        }
    }
    __syncthreads();

    float m1[4] = {-3.4e38f, -3.4e38f, -3.4e38f, -3.4e38f};
    float m2[4] = {-3.4e38f, -3.4e38f, -3.4e38f, -3.4e38f};
    int   i1[4] = {0, 0, 0, 0};

    half8 ahA[8], ahB[8];
    auto loadbuf = [&](half8* buf, int ri) {
        const char* p = e2 + (size_t)ri * 8192;
        #pragma unroll
        for (int kc = 0; kc < 8; ++kc)
            buf[kc] = *(const half8*)(p + kc * 1024);
    };
    auto compute = [&](const half8* ah, int ri) {
        float4 nrm = *(const float4*)&nlds[ri * 16 + ((l >> 4) << 2)];
        f32x4 z = {0.f, 0.f, 0.f, 0.f};
        f32x4 aA[4] = {z, z, z, z};
        #pragma unroll
        for (int kc = 0; kc < 8; ++kc) {
            #pragma unroll
            for (int nt = 0; nt < 4; ++nt)
                aA[nt] = MFH(ah[kc], bx[nt][kc], aA[nt]);
        }
        int c0 = h * 1024 + ri * 16 + ((l >> 4) << 2);
        float nr[4] = {nrm.x, nrm.y, nrm.z, nrm.w};
        #pragma unroll
        for (int nt = 0; nt < 4; ++nt) {
            #pragma unroll
            for (int reg = 0; reg < 4; ++reg) {
                float sc = 2.f * aA[nt][reg] - nr[reg];
                int code = c0 + reg;
                if (sc > m1[nt]) { m2[nt] = m1[nt]; m1[nt] = sc; i1[nt] = code; }
                else             { m2[nt] = fmaxf(m2[nt], sc); }
            }
        }
    };

    loadbuf(ahA, 0);
    for (int ri = 0; ri < 64; ri += 2) {
        loadbuf(ahB, ri + 1);
        compute(ahA, ri);
        if (ri + 2 < 64) loadbuf(ahA, ri + 2);
        compute(ahB, ri + 1);
    }

    #pragma unroll
    for (int nt = 0; nt < 4; ++nt) {
        float a1 = m1[nt], a2 = m2[nt];
        int   ai = i1[nt];
        #pragma unroll
        for (int off = 16; off <= 32; off <<= 1) {
            float o1 = __shfl_xor(a1, off);
            int   oi = __shfl_xor(ai, off);
            float o2 = __shfl_xor(a2, off);
            if (o1 > a1)       { a2 = fmaxf(a1, o2); a1 = o1; ai = oi; }
            else if (o1 == a1) { if (oi < ai) ai = oi; a2 = a1; }
            else               { a2 = fmaxf(a2, o1); }
        }
        if (l < 16) {
            int wi = nt * 16 + l;
            int hi_ = 4 * q + w;
            int n = (bi << 12) + (wi << 6) + hi_;
            keyh[((size_t)h << 16) + n] = ((u64)enc_f(a1) << 32) | (unsigned)(~ai);
            m2h[(h << 16) + n] = a2;
        }
    }
}

// grid 256: 2-way union top-2 merge -> ids + LDS-aggregated histogram + near-tie
// flags. LDS hist caps hot-code global atomics at <=256 per block (was ~2600
// same-address serialized adds chip-wide).
__global__ __launch_bounds__(256) void k_merge(
    const u64* __restrict__ keyh, const float* __restrict__ m2h,
    float* __restrict__ out, int* __restrict__ icnt,
    unsigned* __restrict__ rcnt, int* __restrict__ rlist)
{
    __shared__ int hist[D_CODES];
    const int t = threadIdx.x;
    #pragma unroll
    for (int j = 0; j < 8; ++j) hist[j * 256 + t] = 0;
    __syncthreads();
    int n = blockIdx.x * 256 + t;
    u64 kA = keyh[n], kB = keyh[65536 + n];
    float m2A = m2h[n], m2B = m2h[65536 + n];
    bool wA = kA >= kB;
    u64 kW = wA ? kA : kB, kL = wA ? kB : kA;
    float m2w = wA ? m2A : m2B;
    float sW = dec_f((unsigned)(kW >> 32));
    float sL = dec_f((unsigned)(kL >> 32));
    int code = (int)(~(unsigned)kW);
    out[IDS_OFF + n] = (float)code;
    atomicAdd(&hist[code], 1);
    float gap = sW - fmaxf(m2w, sL);
    if (gap < TAU) {
        unsigned j = atomicAdd(rcnt, 1u);
        if (j < RCAP) rlist[j] = n;
    }
    __syncthreads();
    #pragma unroll
    for (int j = 0; j < 8; ++j) {
        int c = hist[j * 256 + t];
        if (c) atomicAdd(&icnt[j * 256 + t], c);
    }
}

// grid 512: exact fp32 rescore of flagged pixels (x gathered directly; etg coalesced)
__global__ __launch_bounds__(256) void k_rescue(
    const float* __restrict__ x, const float* __restrict__ etg,
    const float* __restrict__ norms, const unsigned* __restrict__ rcnt,
    const int* __restrict__ rlist, float* __restrict__ out,
    int* __restrict__ icnt)
{
    __shared__ float xs[8][257];
    __shared__ int nn[8];
    __shared__ u64 rk[4][8];
    const int t = threadIdx.x;
    const int l = t & 63;
    const int w = t >> 6;
    int nf = (int)min(*rcnt, (unsigned)RCAP);
    int nch = (nf + 7) >> 3;
    for (int chunk = blockIdx.x; chunk < nch; chunk += gridDim.x) {
        __syncthreads();
        if (t < 8) {
            int idx = chunk * 8 + t;
            nn[t] = rlist[idx < nf ? idx : (nf - 1)];
        }
        __syncthreads();
        #pragma unroll
        for (int p = 0; p < 8; ++p) {
            int n = nn[p];
            int bi = n >> 12, wi = (n >> 6) & 63, hi = n & 63;
            xs[p][t] = x[((size_t)(bi * C_DIM + t)) * 4096 + hi * 64 + wi];
        }
        __syncthreads();
        u64 bk[8];
        #pragma unroll
        for (int p = 0; p < 8; ++p) bk[p] = 0ull;
        #pragma unroll
        for (int rep = 0; rep < 2; ++rep) {
            const int d0 = rep * 1024 + t * 4;
            f32x4 acc[8];
            #pragma unroll
            for (int p = 0; p < 8; ++p) acc[p] = (f32x4){0.f, 0.f, 0.f, 0.f};
            for (int c = 0; c < C_DIM; ++c) {
                float4 e4 = *(const float4*)(etg + (size_t)c * D_CODES + d0);
                f32x4 ev = {e4.x, e4.y, e4.z, e4.w};
                #pragma unroll
                for (int p = 0; p < 8; ++p)
                    acc[p] += xs[p][c] * ev;
            }
            float4 nr = *(const float4*)(norms + d0);
            float nrr[4] = {nr.x, nr.y, nr.z, nr.w};
            #pragma unroll
            for (int p = 0; p < 8; ++p) {
                #pragma unroll
                for (int j = 0; j < 4; ++j) {
                    float sc = 2.f * acc[p][j] - nrr[j];
                    u64 key = ((u64)enc_f(sc) << 32) | (unsigned)(~(d0 + j));
                    if (key > bk[p]) bk[p] = key;
                }
            }
        }
        #pragma unroll
        for (int p = 0; p < 8; ++p) {
            u64 k0 = bk[p];
            #pragma unroll
            for (int o = 32; o; o >>= 1) {
                u64 ok = __shfl_down(k0, o);
                if (ok > k0) k0 = ok;
            }
            if (l == 0) rk[w][p] = k0;
        }
        __syncthreads();
        if (t < 8 && chunk * 8 + t < nf) {
            u64 k0 = rk[0][t];
            if (rk[1][t] > k0) k0 = rk[1][t];
            if (rk[2][t] > k0) k0 = rk[2][t];
            if (rk[3][t] > k0) k0 = rk[3][t];
            int n = nn[t];
            int newid = (int)(~(unsigned)k0);
            int old = (int)out[IDS_OFF + n];
            if (newid != old) {
                out[IDS_OFF + n] = (float)newid;
                atomicAdd(&icnt[old], -1);
                atomicAdd(&icnt[newid], 1);
            }
        }
    }
}

// single block: offsets + sub-block table + cntf + ntot
__global__ __launch_bounds__(256) void k_prefix(const int* __restrict__ icnt,
                                                const float* __restrict__ cs_in,
                                                int* __restrict__ offs,
                                                int* __restrict__ curs,
                                                float* __restrict__ cntf,
                                                int* __restrict__ sbcode,
                                                int* __restrict__ sbstart,
                                                int* __restrict__ sbinfo,
                                                int* __restrict__ nsbtot,
                                                float* __restrict__ ntot) {
    __shared__ int ps[256];
    __shared__ float fs[256];
    const int t = threadIdx.x;
    int c[8], o8[8];
    int s = 0;
    #pragma unroll
    for (int j = 0; j < 8; ++j) c[j] = icnt[t * 8 + j];
    #pragma unroll
    for (int j = 0; j < 8; ++j) { int tmp = c[j]; c[j] = s; s += tmp; }
    ps[t] = s;
    __syncthreads();
    for (int off = 1; off < 256; off <<= 1) {
        int v = (t >= off) ? ps[t - off] : 0;
        __syncthreads();
        ps[t] += v;
        __syncthreads();
    }
    int base = ps[t] - s;
    #pragma unroll
    for (int j = 0; j < 8; ++j) {
        int o = base + c[j];
        o8[j] = o;
        offs[t * 8 + j] = o;
        curs[t * 8 + j] = o;
        cntf[t * 8 + j] = (float)(icnt[t * 8 + j]);
    }
    int s2 = 0;
    int nb[8];
    #pragma unroll
    for (int j = 0; j < 8; ++j) {
        int cnt = icnt[t * 8 + j];
        nb[j] = (cnt + 255) >> 8;
        s2 += nb[j];
    }
    __syncthreads();
    ps[t] = s2;
    __syncthreads();
    for (int off = 1; off < 256; off <<= 1) {
        int v = (t >= off) ? ps[t - off] : 0;
        __syncthreads();
        ps[t] += v;
        __syncthreads();
    }
    int pos = ps[t] - s2;
    #pragma unroll
    for (int j = 0; j < 8; ++j) {
        int code = t * 8 + j;
        int cnt = icnt[code];
        int n = nb[j];
        for (int k = 0; k < n; ++k) {
            sbcode[pos]  = code;
            sbstart[pos] = o8[j] + k * 256;
            int len = cnt - k * 256; if (len > 256) len = 256;
            sbinfo[pos]  = len | ((n > 1) ? (1 << 16) : 0);
            ++pos;
        }
    }
    if (t == 255) *nsbtot = ps[255];
    // ntot = 0.99 * sum(cs_in) + 0.01 * 65536 (assignment-independent)
    float s3 = 0.f;
    #pragma unroll
    for (int j = 0; j < 8; ++j) s3 += cs_in[t * 8 + j];
    fs[t] = s3;
    __syncthreads();
    for (int o = 128; o; o >>= 1) { if (t < o) fs[t] += fs[t + o]; __syncthreads(); }
    if (t == 0) *ntot = MOM * fs[0] + ONE_M * 65536.0f;
}

__global__ __launch_bounds__(256) void k_scatter(const float* __restrict__ out,
                                                 int* __restrict__ curs,
                                                 int* __restrict__ plist) {
    int n = blockIdx.x * 256 + threadIdx.x;
    int id = (int)out[IDS_OFF + n];
    int pos = atomicAdd(&curs[id], 1);
    plist[pos] = n;
}

// grid-stride over sub-blocks: dense esum partials (fp16 xt2 reads, fp32 accum)
__global__ __launch_bounds__(256) void k_esum(
    const unsigned short* __restrict__ xt2, const float* __restrict__ embed,
    const float* __restrict__ norms, const int* __restrict__ sbcode,
    const int* __restrict__ sbstart, const int* __restrict__ sbinfo,
    const int* __restrict__ plist, const int* __restrict__ nsbtot,
    float* __restrict__ esum, float* __restrict__ lossp)
{
    __shared__ int   ns[256];
    __shared__ float red[256];
    const _Float16* xth = (const _Float16*)xt2;
    const int t = threadIdx.x;
    const int total = *nsbtot;
    for (int sb = blockIdx.x; sb < total; sb += gridDim.x) {
        const int d     = sbcode[sb];
        const int start = sbstart[sb];
        const int info  = sbinfo[sb];
        const int len   = info & 0xFFFF;
        const bool multi = (info >> 16) != 0;
        __syncthreads();
        if (t < len) ns[t] = plist[start + t];
        __syncthreads();
        float acc = 0.f;
        #pragma unroll 8
        for (int i = 0; i < len; ++i)
            acc += (float)xth[(size_t)ns[i] * C_DIM + t];
        if (multi) atomicAdd(&esum[(size_t)t * D_CODES + d], acc);
        else       esum[(size_t)t * D_CODES + d] = acc;
        red[t] = acc * embed[(size_t)d * C_DIM + t];
        __syncthreads();
        for (int o = 128; o; o >>= 1) {
            if (t < o) red[t] += red[t + o];
            __syncthreads();
        }
        if (t == 0) lossp[sb] = 2.f * red[0] - (float)len * norms[d];
    }
}

// grid 3073: blocks 0-1023 quantized write; 1024-3071 embed-EMA+new_embed (+NCS);
// block 3072 loss
__global__ __launch_bounds__(256) void k_post(
    const float* __restrict__ embed, const float* __restrict__ cs_in,
    const float* __restrict__ cntf, const float* __restrict__ embed_avg,
    const float* __restrict__ esum, const float* __restrict__ ntotp,
    const float* __restrict__ lossp, const float* __restrict__ sumx2p,
    float* __restrict__ out)
{
    __shared__ float shm[8456];       // quant: ids_s[64]+es[32][257]; final: sm[256]
    const int b = blockIdx.x;
    const int t = threadIdx.x;
    if (b < 1024) {
        int* ids_s = (int*)shm;
        float (*es)[257] = (float(*)[257])(shm + 64);
        const int bi = b >> 6;
        const int hi = b & 63;
        const int wl = t & 31;
        const int cg = t >> 5;
        if (t < 64) ids_s[t] = (int)out[IDS_OFF + ((size_t)bi << 12) + (t << 6) + hi];
        __syncthreads();
        #pragma unroll
        for (int pass = 0; pass < 2; ++pass) {
            #pragma unroll 8
            for (int p = 0; p < 32; ++p) {
                es[p][t] = embed[(size_t)ids_s[pass * 32 + p] * C_DIM + t];
            }
            __syncthreads();
            #pragma unroll 8
            for (int k = 0; k < 32; ++k) {
                int ch = k * 8 + cg;
                out[Q_OFF + ((size_t)(bi * C_DIM + ch)) * 4096 + hi * 64 + pass * 32 + wl]
                    = es[wl][ch];
            }
            __syncthreads();
        }
    } else if (b < 3072) {
        int bb = b - 1024;
        int ch = bb >> 3;
        int d  = ((bb & 7) << 8) + t;
        float ntot = *ntotp;
        float ncs  = MOM * cs_in[d] + ONE_M * cntf[d];
        if (bb < 8) out[NCS_OFF + d] = ncs;
        float csm  = ntot * (ncs + EPSI) / (ntot + (float)D_CODES * EPSI);
        size_t i = (size_t)ch * D_CODES + d;
        float nea = MOM * embed_avg[i] + ONE_M * esum[i];
        out[NEA_OFF + i] = nea;
        out[NE_OFF + (size_t)d * C_DIM + ch] = nea / csm;
    } else {
        float* sm = shm;
        float s1 = 0.f;
        for (int i = t; i < 1024; i += 256) s1 += sumx2p[i];
        float s2 = 0.f;
        for (int i = t; i < SBCAP; i += 256) s2 += lossp[i];
        sm[t] = s1 - s2;
        __syncthreads();
        for (int o = 128; o; o >>= 1) { if (t < o) sm[t] += sm[t + o]; __syncthreads(); }
        if (t == 0) out[LOSS_OFF] = sm[0] / 16777216.f;
    }
}

extern "C" void kernel_launch(void* const* d_in, const int* in_sizes, int n_in,
                              void* d_out, int out_size, void* d_ws, size_t ws_size,
                              hipStream_t stream) {
    const float* x     = (const float*)d_in[0];
    const float* embed = (const float*)d_in[1];
    const float* cs    = (const float*)d_in[2];
    const float* ea    = (const float*)d_in[3];
    float* out = (float*)d_out;
    float* ws  = (float*)d_ws;
    int*      icnt    = (int*)(ws + WS_ICNT);
    float*    cntf    = ws + WS_CNTF;
    int*      offs    = (int*)(ws + WS_OFFS);
    int*      curs    = (int*)(ws + WS_CURS);
    float*    sumx2p  = ws + WS_SUMX2;
    float*    ntot    = ws + WS_NTOT;
    unsigned* rcnt    = (unsigned*)(ws + WS_RCNT);
    int*      nsbtot  = (int*)(ws + WS_NSB);
    float*    norms   = ws + WS_NORMS;
    int*      rlist   = (int*)(ws + WS_RLIST);
    float*    esum    = ws + WS_ESUM;
    float*    e2      = ws + WS_E2;
    u64*      keyh    = (u64*)(ws + WS_KEYH);
    float*    m2h     = ws + WS_M2H;
    int*      plist   = (int*)(ws + WS_PLIST);
    int*      sbcode  = (int*)(ws + WS_SBCODE);
    int*      sbstart = (int*)(ws + WS_SBSTART);
    int*      sbinfo  = (int*)(ws + WS_SBINFO);
    float*    lossp   = ws + WS_LOSSP;
    unsigned short* xt2 = (unsigned short*)(out + Q_OFF); // fp16 xT, overwritten by k_post
    float*    etg     = out + NEA_OFF;  // embed^T scratch, overwritten by k_post

    k_init<<<2048, 256, 0, stream>>>(embed, x, e2, norms, esum, icnt, lossp, rcnt,
                                     etg, xt2, sumx2p);
    k_main<<<512, 256, 0, stream>>>(xt2, e2, norms, keyh, m2h);
    k_merge<<<256, 256, 0, stream>>>(keyh, m2h, out, icnt, rcnt, rlist);
    k_rescue<<<512, 256, 0, stream>>>(x, etg, norms, rcnt, rlist, out, icnt);
    k_prefix<<<1, 256, 0, stream>>>(icnt, cs, offs, curs, cntf, sbcode, sbstart,
                                    sbinfo, nsbtot, ntot);
    k_scatter<<<256, 256, 0, stream>>>(out, curs, plist);
    k_esum<<<SBCAP, 256, 0, stream>>>(xt2, embed, norms, sbcode, sbstart, sbinfo,
                                      plist, nsbtot, esum, lossp);
    k_post<<<3073, 256, 0, stream>>>(embed, cs, cntf, ea, esum, ntot, lossp,
                                     sumx2p, out);
}